// Round 6
// baseline (266.612 us; speedup 1.0000x reference)
//
#include <hip/hip_runtime.h>
#include <cmath>

#define H_DIM 75
#define W_DIM 100
#define HW 7500
#define KSEL 2000
#define BATCH 8
#define CIN 512
#define FDIM 128

typedef short v4s __attribute__((ext_vector_type(4)));
typedef short v8s __attribute__((ext_vector_type(8)));
typedef float v16f __attribute__((ext_vector_type(16)));

__device__ __forceinline__ unsigned int map_key(float f) {
  unsigned int u = __float_as_uint(f);
  return (u & 0x80000000u) ? ~u : (u | 0x80000000u);
}

__device__ __forceinline__ float fast_tanh(float x) {
  float e = __expf(2.0f * x);
  return 1.0f - 2.0f * __builtin_amdgcn_rcpf(e + 1.0f);
}

__device__ __forceinline__ unsigned short bf16_rne(float v) {
  unsigned int u = __float_as_uint(v);
  unsigned int r = u + 0x7FFFu + ((u >> 16) & 1u);
  return (unsigned short)(r >> 16);
}
__device__ __forceinline__ float bf16_to_f(unsigned short h) {
  return __uint_as_float(((unsigned int)h) << 16);
}

// K1 (fused): blocks 0..7 per-batch top-K (radix select with per-wave
// privatized histograms -> low LDS-atomic contention) + packed scan (exact
// lax.top_k+sort semantics) + neighbor lists. Blocks 8..15 split w1 AND w2
// into transposed bf16 hi/lo planes for the MFMA GEMMs.
// r4/r5 lesson: the fused global-scatter gemm1 is TA-request-rate bound
// (per-instruction divergent-address cost; occupancy/latency tricks null)
// -> feat path reverted to coalesced plane-staged gather (K2b) + nft gemm1.
__global__ __launch_bounds__(1024) void topk_nbr_kernel(
    const float* __restrict__ pred, const float* __restrict__ w1,
    const float* __restrict__ w2,
    int* __restrict__ off_ws, float* __restrict__ out_idx,
    unsigned short* __restrict__ nbr, unsigned char* __restrict__ cnt,
    unsigned short* __restrict__ w1t_hi, unsigned short* __restrict__ w1t_lo,
    unsigned short* __restrict__ w2t_hi, unsigned short* __restrict__ w2t_lo)
{
  __shared__ unsigned int keys[HW];        // 30 KB; reused: pos_of + s_idx
  __shared__ unsigned int whist[16 * 256]; // per-wave histograms, 16 KB
  __shared__ unsigned int hist[256];
  __shared__ unsigned int partials[16];
  __shared__ unsigned int s_prefix, s_kth;
  const int tid = threadIdx.x;

  if (blockIdx.x >= BATCH) {               // weight split: 8 blocks x 1024 thr
    int base = (blockIdx.x - BATCH) * 1024 + tid;
    for (int e = base; e < CIN * FDIM + FDIM * FDIM; e += 8 * 1024) {
      if (e < CIN * FDIM) {
        int k = e & (CIN - 1), f = e >> 9;   // k-inner: coalesced writes
        float v = w1[k * FDIM + f];
        unsigned short hi = bf16_rne(v);
        unsigned short lo = bf16_rne(v - bf16_to_f(hi));
        w1t_hi[(size_t)f * CIN + k] = hi;
        w1t_lo[(size_t)f * CIN + k] = lo;
      } else {
        int e2 = e - CIN * FDIM;
        int k = e2 & (FDIM - 1), f = e2 >> 7;
        float v = w2[k * FDIM + f];
        unsigned short hi = bf16_rne(v);
        unsigned short lo = bf16_rne(v - bf16_to_f(hi));
        w2t_hi[(size_t)f * FDIM + k] = hi;
        w2t_lo[(size_t)f * FDIM + k] = lo;
      }
    }
    return;
  }

  const int b = blockIdx.x;
  const int lane = tid & 63, w = tid >> 6;
  const float* scores = pred + (size_t)b * 3 * HW;  // channel 0 of predict
  for (int i = tid; i < HW; i += 1024) keys[i] = map_key(scores[i]);
  if (tid == 0) { s_prefix = 0u; s_kth = KSEL; }
  __syncthreads();

  // radix select, MSB-first, 8 bits/round
  for (int shift = 24; shift >= 0; shift -= 8) {
    for (int i = tid; i < 16 * 256; i += 1024) whist[i] = 0u;
    __syncthreads();
    unsigned int pref = s_prefix;
    unsigned int maskhi = (shift == 24) ? 0u : (0xFFFFFFFFu << (shift + 8));
    for (int i = tid; i < HW; i += 1024) {
      unsigned int k = keys[i];
      if ((k & maskhi) == pref)
        atomicAdd(&whist[w * 256 + ((k >> shift) & 0xFFu)], 1u);
    }
    __syncthreads();
    if (tid < 256) {
      unsigned int s = 0;
      #pragma unroll
      for (int ww = 0; ww < 16; ++ww) s += whist[ww * 256 + tid];
      hist[tid] = s;
    }
    __syncthreads();
    if (tid < 64) {
      unsigned int b0 = hist[tid * 4], b1 = hist[tid * 4 + 1];
      unsigned int b2 = hist[tid * 4 + 2], b3 = hist[tid * 4 + 3];
      unsigned int kth = s_kth;
      unsigned int T = b0 + b1 + b2 + b3;
      #pragma unroll
      for (int off = 1; off < 64; off <<= 1) {
        unsigned int t = __shfl_down(T, off, 64);
        if (tid + off < 64) T += t;         // inclusive suffix of lane totals
      }
      unsigned int U = __shfl_down(T, 1, 64);
      if (tid == 63) U = 0u;                // suffix strictly after this lane
      unsigned int s3 = b3 + U, s2 = b2 + s3, s1 = b1 + s2, s0 = b0 + s1;
      if (s0 >= kth && s1 < kth) { s_prefix = pref | ((unsigned)(4 * tid + 0) << shift); s_kth = kth - s1; }
      if (s1 >= kth && s2 < kth) { s_prefix = pref | ((unsigned)(4 * tid + 1) << shift); s_kth = kth - s2; }
      if (s2 >= kth && s3 < kth) { s_prefix = pref | ((unsigned)(4 * tid + 2) << shift); s_kth = kth - s3; }
      if (s3 >= kth && U  < kth) { s_prefix = pref | ((unsigned)(4 * tid + 3) << shift); s_kth = kth - U; }
    }
    __syncthreads();
  }
  const unsigned int thresh = s_prefix;

  // selection flags: gt in low 16 bits, eq in high 16, packed
  unsigned int local[8];
  unsigned int sum = 0;
  #pragma unroll
  for (int e = 0; e < 8; ++e) {
    int i = tid * 8 + e;
    unsigned int p = 0;
    if (i < HW) {
      unsigned int ky = keys[i];
      if (ky > thresh) p = 1u;
      else if (ky == thresh) p = (1u << 16);
    }
    local[e] = p; sum += p;
  }
  __syncthreads();   // keys dead — overlay
  short* pos_of  = (short*)keys;
  int*   s_idx_sh = (int*)((char*)keys + 15000);
  for (int i = tid; i < HW; i += 1024) pos_of[i] = -1;

  // two-level exclusive prefix scan
  unsigned int inc = sum;
  #pragma unroll
  for (int off = 1; off < 64; off <<= 1) {
    unsigned int t = __shfl_up(inc, off, 64);
    if (lane >= off) inc += t;
  }
  if (lane == 63) partials[w] = inc;
  __syncthreads();
  if (tid < 16) {
    unsigned int v = partials[tid];
    #pragma unroll
    for (int off = 1; off < 16; off <<= 1) {
      unsigned int t = __shfl_up(v, off, 64);
      if (tid >= off) v += t;
    }
    partials[tid] = v;
  }
  __syncthreads();
  unsigned int total = partials[15];
  unsigned int run = (w ? partials[w - 1] : 0u) + inc - sum;
  unsigned int ties = (unsigned int)KSEL - (total & 0xFFFFu);
  #pragma unroll
  for (int e = 0; e < 8; ++e) {
    int i = tid * 8 + e;
    unsigned int p = local[e];
    unsigned int gt_pref = run & 0xFFFFu;
    unsigned int eq_pref = run >> 16;
    bool sel = (p & 1u) || (((p >> 16) != 0u) && eq_pref < ties);
    if (sel) {
      unsigned int pos = gt_pref + (eq_pref < ties ? eq_pref : ties);
      off_ws[b * KSEL + pos] = (i % H_DIM) * W_DIM + i / H_DIM;  // gather quirk
      out_idx[b * KSEL + pos] = (float)i;
      s_idx_sh[pos] = i;
      pos_of[i] = (short)pos;
    }
    run += p;
  }
  __syncthreads();

  // neighbor lists; rows padded to 9 (pad=0) so consumers load unconditionally
  for (int i = tid; i < KSEL; i += 1024) {
    int q = s_idx_sh[i];
    int py = q / W_DIM, px = q % W_DIM;
    unsigned short tmp[9];
    int c = 0;
    #pragma unroll
    for (int dy = -1; dy <= 1; ++dy) {
      int y = py + dy;
      if ((unsigned)y >= (unsigned)H_DIM) continue;
      #pragma unroll
      for (int dx = -1; dx <= 1; ++dx) {
        int x = px + dx;
        if ((unsigned)x >= (unsigned)W_DIM) continue;
        short p = pos_of[y * W_DIM + x];
        if (p >= 0) tmp[c++] = (unsigned short)p;
      }
    }
    #pragma unroll
    for (int t = 0; t < 9; ++t)
      nbr[(size_t)(b * KSEL + i) * 9 + t] = (t < c) ? tmp[t] : (unsigned short)0;
    cnt[b * KSEL + i] = (unsigned char)c;
  }
}

// K2: gather+clip via LDS plane staging (coalesced float4 plane read; the
// scatter happens in LDS where it's cheap); emits bf16 hi/lo planes [c][n].
__global__ __launch_bounds__(512) void gather_kernel(
    const float* __restrict__ feat, const int* __restrict__ off_ws,
    unsigned short* __restrict__ nft_hi, unsigned short* __restrict__ nft_lo)
{
  __shared__ __align__(16) float s_plane[HW];
  const int b = blockIdx.y;
  const int c = blockIdx.x;
  const int tid = threadIdx.x;
  const float4* p4 = (const float4*)(feat + ((size_t)b * CIN + c) * HW);
  float4* sp4 = (float4*)s_plane;
  #pragma unroll
  for (int i = tid; i < HW / 4; i += 512)
    sp4[i] = p4[i];
  __syncthreads();
  if (tid < KSEL / 4) {
    const uint4* o4 = (const uint4*)off_ws + (size_t)b * (KSEL / 4);
    uint4 o = o4[tid];
    float v0 = fminf(fmaxf(s_plane[o.x], 0.f), 6.f);
    float v1 = fminf(fmaxf(s_plane[o.y], 0.f), 6.f);
    float v2 = fminf(fmaxf(s_plane[o.z], 0.f), 6.f);
    float v3 = fminf(fmaxf(s_plane[o.w], 0.f), 6.f);
    ushort4 h, l;
    h.x = bf16_rne(v0); l.x = bf16_rne(v0 - bf16_to_f(h.x));
    h.y = bf16_rne(v1); l.y = bf16_rne(v1 - bf16_to_f(h.y));
    h.z = bf16_rne(v2); l.z = bf16_rne(v2 - bf16_to_f(h.z));
    h.w = bf16_rne(v3); l.w = bf16_rne(v3 - bf16_to_f(h.w));
    size_t row = ((size_t)b * CIN + c) * KSEL;
    ((ushort4*)&nft_hi[row])[tid] = h;
    ((ushort4*)&nft_lo[row])[tid] = l;
  }
}

// K3: G = clip(NF) @ w1, split-precision bf16 MFMA (hi*hi + hi*lo + lo*hi).
// 64x128 tile, 4 waves. A staged in double-buffered LDS (coalesced 16B reads
// from nft); B read directly from L2-resident w1t.
__global__ __launch_bounds__(256) void gemm1_mfma(
    const unsigned short* __restrict__ nft_hi,
    const unsigned short* __restrict__ nft_lo,
    const unsigned short* __restrict__ w1t_hi,
    const unsigned short* __restrict__ w1t_lo,
    float* __restrict__ G)
{
  __shared__ unsigned short a_hi[2][64][20], a_lo[2][64][20];  // 10 KB
  const int b = blockIdx.y;
  const int n0 = blockIdx.x * 64;
  const int tid = threadIdx.x;
  const int lane = tid & 63, w = tid >> 6;
  const int wr = w & 1, wc = w >> 1;
  const int q = lane >> 5, m = lane & 31;
  v16f acc0, acc1;
  #pragma unroll
  for (int i = 0; i < 16; ++i) { acc0[i] = 0.f; acc1[i] = 0.f; }
  const unsigned short* nh = nft_hi + (size_t)b * CIN * KSEL;
  const unsigned short* nl = nft_lo + (size_t)b * CIN * KSEL;
  const int an = wr * 32 + m;
  const int f0 = wc * 64 + m;
  const int n_st = tid & 63, ks = (tid >> 6) * 4;

  #pragma unroll
  for (int j = 0; j < 4; ++j) {               // prologue: stage chunk 0
    size_t gi = (size_t)(ks + j) * KSEL + n0 + n_st;
    a_hi[0][n_st][ks + j] = nh[gi];
    a_lo[0][n_st][ks + j] = nl[gi];
  }
  __syncthreads();

  for (int k0 = 0; k0 < CIN; k0 += 16) {
    const int p = (k0 >> 4) & 1;
    if (k0 + 16 < CIN) {                      // stage next into other buffer
      #pragma unroll
      for (int j = 0; j < 4; ++j) {
        size_t gi = (size_t)(k0 + 16 + ks + j) * KSEL + n0 + n_st;
        a_hi[p ^ 1][n_st][ks + j] = nh[gi];
        a_lo[p ^ 1][n_st][ks + j] = nl[gi];
      }
    }
    v4s ah0 = *(const v4s*)&a_hi[p][an][q * 8];
    v4s ah1 = *(const v4s*)&a_hi[p][an][q * 8 + 4];
    v4s al0 = *(const v4s*)&a_lo[p][an][q * 8];
    v4s al1 = *(const v4s*)&a_lo[p][an][q * 8 + 4];
    v8s avh = __builtin_shufflevector(ah0, ah1, 0, 1, 2, 3, 4, 5, 6, 7);
    v8s avl = __builtin_shufflevector(al0, al1, 0, 1, 2, 3, 4, 5, 6, 7);
    v8s b0h = *(const v8s*)&w1t_hi[(size_t)f0 * CIN + k0 + q * 8];
    v8s b0l = *(const v8s*)&w1t_lo[(size_t)f0 * CIN + k0 + q * 8];
    v8s b1h = *(const v8s*)&w1t_hi[(size_t)(f0 + 32) * CIN + k0 + q * 8];
    v8s b1l = *(const v8s*)&w1t_lo[(size_t)(f0 + 32) * CIN + k0 + q * 8];
    acc0 = __builtin_amdgcn_mfma_f32_32x32x16_bf16(avh, b0h, acc0, 0, 0, 0);
    acc0 = __builtin_amdgcn_mfma_f32_32x32x16_bf16(avh, b0l, acc0, 0, 0, 0);
    acc0 = __builtin_amdgcn_mfma_f32_32x32x16_bf16(avl, b0h, acc0, 0, 0, 0);
    acc1 = __builtin_amdgcn_mfma_f32_32x32x16_bf16(avh, b1h, acc1, 0, 0, 0);
    acc1 = __builtin_amdgcn_mfma_f32_32x32x16_bf16(avh, b1l, acc1, 0, 0, 0);
    acc1 = __builtin_amdgcn_mfma_f32_32x32x16_bf16(avl, b1h, acc1, 0, 0, 0);
    __syncthreads();
  }
  float* ob = G + (size_t)b * KSEL * FDIM;
  #pragma unroll
  for (int reg = 0; reg < 16; ++reg) {
    int row = n0 + wr * 32 + (reg & 3) + 8 * (reg >> 2) + 4 * q;
    if (row < KSEL) {
      ob[(size_t)row * FDIM + f0]      = acc0[reg];
      ob[(size_t)row * FDIM + f0 + 32] = acc1[reg];
    }
  }
}

// K4 (fused x1+gemm2): phase 1 computes x1 rows n0..n0+63 (9-neighbor G
// gather + b1), writes fp32 x1 for the out kernel, and drops the bf16 hi/lo
// split straight into XOR-swizzled LDS (col ^ ((row&15)<<3) -> 2-way bank
// aliasing = free). Phase 2 is the split-precision MFMA x1 @ w2 reading A
// from LDS. Deletes the 16.4 MB x1h/x1l HBM roundtrip + one launch.
__global__ __launch_bounds__(256) void gemm2_fused(
    const float* __restrict__ G, const float* __restrict__ b1,
    const unsigned short* __restrict__ nbr, const unsigned char* __restrict__ cnt,
    const unsigned short* __restrict__ w2t_hi,
    const unsigned short* __restrict__ w2t_lo,
    float* __restrict__ x1, float* __restrict__ Hm)
{
  __shared__ __align__(16) unsigned short xh[64][FDIM];  // 16 KB
  __shared__ __align__(16) unsigned short xl[64][FDIM];  // 16 KB
  const int b = blockIdx.y;
  const int n0 = blockIdx.x * 64;
  const int tid = threadIdx.x;
  const int g = tid >> 5, lane32 = tid & 31;
  const float4* G4 = (const float4*)G + (size_t)b * KSEL * 32;

  #pragma unroll 2
  for (int rr = 0; rr < 8; ++rr) {
    const int r = rr * 8 + g;
    const int node = n0 + r;
    const int nodec = (node > KSEL - 1) ? KSEL - 1 : node;
    const size_t bi = (size_t)b * KSEL + nodec;
    const unsigned short* nb = nbr + bi * 9;
    unsigned short idx[9];
    #pragma unroll
    for (int t = 0; t < 9; ++t) idx[t] = nb[t];
    const int c = cnt[bi];
    float4 v[9];
    #pragma unroll
    for (int t = 0; t < 9; ++t) v[t] = G4[(size_t)idx[t] * 32 + lane32];
    float4 acc = ((const float4*)b1)[nodec * 32 + lane32];
    #pragma unroll
    for (int t = 0; t < 9; ++t) {
      float mk = (t < c) ? 1.f : 0.f;
      acc.x = fmaf(v[t].x, mk, acc.x);
      acc.y = fmaf(v[t].y, mk, acc.y);
      acc.z = fmaf(v[t].z, mk, acc.z);
      acc.w = fmaf(v[t].w, mk, acc.w);
    }
    if (node < KSEL) ((float4*)x1)[bi * 32 + lane32] = acc;
    ushort4 h, l;
    h.x = bf16_rne(acc.x); l.x = bf16_rne(acc.x - bf16_to_f(h.x));
    h.y = bf16_rne(acc.y); l.y = bf16_rne(acc.y - bf16_to_f(h.y));
    h.z = bf16_rne(acc.z); l.z = bf16_rne(acc.z - bf16_to_f(h.z));
    h.w = bf16_rne(acc.w); l.w = bf16_rne(acc.w - bf16_to_f(h.w));
    const int cs = (lane32 * 4) ^ ((r & 15) << 3);   // swizzled col (shorts)
    *(ushort4*)&xh[r][cs] = h;
    *(ushort4*)&xl[r][cs] = l;
  }
  __syncthreads();

  const int lane = tid & 63, w = tid >> 6;
  const int wr = w & 1, wc = w >> 1;
  const int q = lane >> 5, m = lane & 31;
  const int ar = wr * 32 + m;            // local A row in LDS
  const int f0 = wc * 64 + m;
  v16f acc0, acc1;
  #pragma unroll
  for (int i = 0; i < 16; ++i) { acc0[i] = 0.f; acc1[i] = 0.f; }
  #pragma unroll
  for (int k0 = 0; k0 < FDIM; k0 += 16) {
    const int ac = (k0 + q * 8) ^ ((ar & 15) << 3);
    v8s avh = *(const v8s*)&xh[ar][ac];
    v8s avl = *(const v8s*)&xl[ar][ac];
    v8s b0h = *(const v8s*)&w2t_hi[(size_t)f0 * FDIM + k0 + q * 8];
    v8s b0l = *(const v8s*)&w2t_lo[(size_t)f0 * FDIM + k0 + q * 8];
    v8s b1h = *(const v8s*)&w2t_hi[(size_t)(f0 + 32) * FDIM + k0 + q * 8];
    v8s b1l = *(const v8s*)&w2t_lo[(size_t)(f0 + 32) * FDIM + k0 + q * 8];
    acc0 = __builtin_amdgcn_mfma_f32_32x32x16_bf16(avh, b0h, acc0, 0, 0, 0);
    acc0 = __builtin_amdgcn_mfma_f32_32x32x16_bf16(avh, b0l, acc0, 0, 0, 0);
    acc0 = __builtin_amdgcn_mfma_f32_32x32x16_bf16(avl, b0h, acc0, 0, 0, 0);
    acc1 = __builtin_amdgcn_mfma_f32_32x32x16_bf16(avh, b1h, acc1, 0, 0, 0);
    acc1 = __builtin_amdgcn_mfma_f32_32x32x16_bf16(avh, b1l, acc1, 0, 0, 0);
    acc1 = __builtin_amdgcn_mfma_f32_32x32x16_bf16(avl, b1h, acc1, 0, 0, 0);
  }
  float* ob = Hm + (size_t)b * KSEL * FDIM;
  #pragma unroll
  for (int reg = 0; reg < 16; ++reg) {
    int row = n0 + wr * 32 + (reg & 3) + 8 * (reg >> 2) + 4 * q;
    if (row < KSEL) {
      ob[(size_t)row * FDIM + f0]      = acc0[reg];
      ob[(size_t)row * FDIM + f0 + 32] = acc1[reg];
    }
  }
}

// K5: out[i] = tanh(b2[i] + x1[i] + sum_{j in nbr(i)} H[j])
__global__ __launch_bounds__(256) void out_kernel(
    const float* __restrict__ Hm, const float* __restrict__ x1,
    const float* __restrict__ b2,
    const unsigned short* __restrict__ nbr, const unsigned char* __restrict__ cnt,
    float* __restrict__ out)
{
  const int g = threadIdx.x >> 5, lane = threadIdx.x & 31;
  const int node = blockIdx.x * 8 + g;
  const int bb = blockIdx.y;
  const size_t bi = (size_t)bb * KSEL + node;
  const unsigned short* nb = nbr + bi * 9;
  unsigned short idx[9];
  #pragma unroll
  for (int t = 0; t < 9; ++t) idx[t] = nb[t];
  const int c = cnt[bi];
  const float4* H4 = (const float4*)Hm + (size_t)bb * KSEL * 32;
  float4 v[9];
  #pragma unroll
  for (int t = 0; t < 9; ++t) v[t] = H4[(size_t)idx[t] * 32 + lane];
  float4 acc = ((const float4*)b2)[node * 32 + lane];
  float4 xv = ((const float4*)x1)[bi * 32 + lane];
  acc.x += xv.x; acc.y += xv.y; acc.z += xv.z; acc.w += xv.w;
  #pragma unroll
  for (int t = 0; t < 9; ++t) {
    float mk = (t < c) ? 1.f : 0.f;
    acc.x = fmaf(v[t].x, mk, acc.x);
    acc.y = fmaf(v[t].y, mk, acc.y);
    acc.z = fmaf(v[t].z, mk, acc.z);
    acc.w = fmaf(v[t].w, mk, acc.w);
  }
  float4 r;
  r.x = fast_tanh(acc.x); r.y = fast_tanh(acc.y);
  r.z = fast_tanh(acc.z); r.w = fast_tanh(acc.w);
  ((float4*)out)[bi * 32 + lane] = r;
}

extern "C" void kernel_launch(void* const* d_in, const int* in_sizes, int n_in,
                              void* d_out, int out_size, void* d_ws, size_t ws_size,
                              hipStream_t stream) {
  const float* feat = (const float*)d_in[0];
  const float* pred = (const float*)d_in[1];
  const float* w1   = (const float*)d_in[2];
  const float* b1   = (const float*)d_in[3];
  const float* w2   = (const float*)d_in[4];
  const float* b2   = (const float*)d_in[5];
  float* out0 = (float*)d_out;                              // (8,2000,128) fp32
  float* out_idx = out0 + (size_t)BATCH * KSEL * FDIM;      // (8,2000) as fp32

  // workspace layout (256B-aligned). Overlay region R: nft hi/lo live until
  // gemm1; x1/Hm live after. w1t/w2t live outside the overlaid span.
  char* ws = (char*)d_ws;
  int*            off_ws = (int*)(ws + 0);                  //  64,000 B
  unsigned short* nbr    = (unsigned short*)(ws + 64256);   // 288,000 B
  unsigned char*  cnt    = (unsigned char*)(ws + 352512);   //  16,000 B
  float*          G      = (float*)(ws + 368640);           // 8,192,000 B
  char*           R      = ws + 8560640;
  unsigned short* nft_hi = (unsigned short*)R;              // 16,384,000 B
  unsigned short* nft_lo = (unsigned short*)(R + 16384000); // 16,384,000 B
  unsigned short* w1t_hi = (unsigned short*)(R + 32768256); // 131,072 B (+slack)
  unsigned short* w1t_lo = (unsigned short*)(R + 32899328); // 131,072 B
  unsigned short* w2t_hi = (unsigned short*)(R + 33030656); //  32,768 B
  unsigned short* w2t_lo = (unsigned short*)(R + 33063424); //  32,768 B
  float*          x1     = (float*)R;                       // 8,192,000 B
  float*          Hm     = (float*)(R + 8388608);           // 8,192,000 B

  topk_nbr_kernel<<<BATCH + 8, 1024, 0, stream>>>(
      pred, w1, w2, off_ws, out_idx, nbr, cnt, w1t_hi, w1t_lo, w2t_hi, w2t_lo);
  gather_kernel<<<dim3(CIN, BATCH), 512, 0, stream>>>(feat, off_ws, nft_hi, nft_lo);
  gemm1_mfma<<<dim3(32, BATCH), 256, 0, stream>>>(nft_hi, nft_lo, w1t_hi, w1t_lo, G);
  gemm2_fused<<<dim3(32, BATCH), 256, 0, stream>>>(G, b1, nbr, cnt, w2t_hi, w2t_lo, x1, Hm);
  out_kernel<<<dim3(KSEL / 8, BATCH), 256, 0, stream>>>(Hm, x1, b2, nbr, cnt, out0);
}

// Round 7
// 233.492 us; speedup vs baseline: 1.1418x; 1.1418x over previous
//
#include <hip/hip_runtime.h>
#include <cmath>

#define H_DIM 75
#define W_DIM 100
#define HW 7500
#define KSEL 2000
#define BATCH 8
#define CIN 512
#define FDIM 128

typedef short v4s __attribute__((ext_vector_type(4)));
typedef short v8s __attribute__((ext_vector_type(8)));
typedef float v16f __attribute__((ext_vector_type(16)));

__device__ __forceinline__ unsigned int map_key(float f) {
  unsigned int u = __float_as_uint(f);
  return (u & 0x80000000u) ? ~u : (u | 0x80000000u);
}

__device__ __forceinline__ float fast_tanh(float x) {
  float e = __expf(2.0f * x);
  return 1.0f - 2.0f * __builtin_amdgcn_rcpf(e + 1.0f);
}

__device__ __forceinline__ unsigned short bf16_rne(float v) {
  unsigned int u = __float_as_uint(v);
  unsigned int r = u + 0x7FFFu + ((u >> 16) & 1u);
  return (unsigned short)(r >> 16);
}
__device__ __forceinline__ float bf16_to_f(unsigned short h) {
  return __uint_as_float(((unsigned int)h) << 16);
}

// K1 (fused): blocks 0..7 per-batch top-K (radix select with per-wave
// privatized histograms) + packed scan (exact lax.top_k+sort semantics) +
// OFF-SORTED permutation (counting sort on y'=i%75: gemm1 tiles read compact
// disjoint plane windows; r1->r3: 333MB->~100MB fetch, -48us) + neighbor
// lists. Blocks 8..15 split w1/w2 into transposed bf16 hi/lo planes.
// Session ledger: r4 split-K atomics regressed; r5 2-waves/SIMD + depth-1
// T14 null; r6 plane-staged gather+gemm1 pair = ~90us, worse than fused ~59.
__global__ __launch_bounds__(1024) void topk_nbr_kernel(
    const float* __restrict__ pred, const float* __restrict__ w1,
    const float* __restrict__ w2,
    int* __restrict__ off2_ws, int* __restrict__ perm_ws,
    float* __restrict__ out_idx,
    unsigned short* __restrict__ nbr, unsigned char* __restrict__ cnt,
    unsigned short* __restrict__ w1t_hi, unsigned short* __restrict__ w1t_lo,
    unsigned short* __restrict__ w2t_hi, unsigned short* __restrict__ w2t_lo)
{
  __shared__ unsigned int keys[HW];        // 30 KB; reused: pos_of + s_idx
  __shared__ unsigned int whist[16 * 256]; // per-wave histograms, 16 KB
  __shared__ unsigned int hist[256];
  __shared__ unsigned int partials[16];
  __shared__ unsigned int s_prefix, s_kth;
  const int tid = threadIdx.x;

  if (blockIdx.x >= BATCH) {               // weight split: 8 blocks x 1024 thr
    int base = (blockIdx.x - BATCH) * 1024 + tid;
    for (int e = base; e < CIN * FDIM + FDIM * FDIM; e += 8 * 1024) {
      if (e < CIN * FDIM) {
        int k = e & (CIN - 1), f = e >> 9;   // k-inner: coalesced writes
        float v = w1[k * FDIM + f];
        unsigned short hi = bf16_rne(v);
        unsigned short lo = bf16_rne(v - bf16_to_f(hi));
        w1t_hi[(size_t)f * CIN + k] = hi;
        w1t_lo[(size_t)f * CIN + k] = lo;
      } else {
        int e2 = e - CIN * FDIM;
        int k = e2 & (FDIM - 1), f = e2 >> 7;
        float v = w2[k * FDIM + f];
        unsigned short hi = bf16_rne(v);
        unsigned short lo = bf16_rne(v - bf16_to_f(hi));
        w2t_hi[(size_t)f * FDIM + k] = hi;
        w2t_lo[(size_t)f * FDIM + k] = lo;
      }
    }
    return;
  }

  const int b = blockIdx.x;
  const int lane = tid & 63, w = tid >> 6;
  const float* scores = pred + (size_t)b * 3 * HW;  // channel 0 of predict
  for (int i = tid; i < HW; i += 1024) keys[i] = map_key(scores[i]);
  if (tid == 0) { s_prefix = 0u; s_kth = KSEL; }
  __syncthreads();

  // radix select, MSB-first, 8 bits/round
  for (int shift = 24; shift >= 0; shift -= 8) {
    for (int i = tid; i < 16 * 256; i += 1024) whist[i] = 0u;
    __syncthreads();
    unsigned int pref = s_prefix;
    unsigned int maskhi = (shift == 24) ? 0u : (0xFFFFFFFFu << (shift + 8));
    for (int i = tid; i < HW; i += 1024) {
      unsigned int k = keys[i];
      if ((k & maskhi) == pref)
        atomicAdd(&whist[w * 256 + ((k >> shift) & 0xFFu)], 1u);
    }
    __syncthreads();
    if (tid < 256) {
      unsigned int s = 0;
      #pragma unroll
      for (int ww = 0; ww < 16; ++ww) s += whist[ww * 256 + tid];
      hist[tid] = s;
    }
    __syncthreads();
    if (tid < 64) {
      unsigned int b0 = hist[tid * 4], b1 = hist[tid * 4 + 1];
      unsigned int b2 = hist[tid * 4 + 2], b3 = hist[tid * 4 + 3];
      unsigned int kth = s_kth;
      unsigned int T = b0 + b1 + b2 + b3;
      #pragma unroll
      for (int off = 1; off < 64; off <<= 1) {
        unsigned int t = __shfl_down(T, off, 64);
        if (tid + off < 64) T += t;         // inclusive suffix of lane totals
      }
      unsigned int U = __shfl_down(T, 1, 64);
      if (tid == 63) U = 0u;                // suffix strictly after this lane
      unsigned int s3 = b3 + U, s2 = b2 + s3, s1 = b1 + s2, s0 = b0 + s1;
      if (s0 >= kth && s1 < kth) { s_prefix = pref | ((unsigned)(4 * tid + 0) << shift); s_kth = kth - s1; }
      if (s1 >= kth && s2 < kth) { s_prefix = pref | ((unsigned)(4 * tid + 1) << shift); s_kth = kth - s2; }
      if (s2 >= kth && s3 < kth) { s_prefix = pref | ((unsigned)(4 * tid + 2) << shift); s_kth = kth - s3; }
      if (s3 >= kth && U  < kth) { s_prefix = pref | ((unsigned)(4 * tid + 3) << shift); s_kth = kth - U; }
    }
    __syncthreads();
  }
  const unsigned int thresh = s_prefix;

  // selection flags: gt in low 16 bits, eq in high 16, packed
  unsigned int local[8];
  unsigned int sum = 0;
  #pragma unroll
  for (int e = 0; e < 8; ++e) {
    int i = tid * 8 + e;
    unsigned int p = 0;
    if (i < HW) {
      unsigned int ky = keys[i];
      if (ky > thresh) p = 1u;
      else if (ky == thresh) p = (1u << 16);
    }
    local[e] = p; sum += p;
  }
  __syncthreads();   // keys dead — overlay
  short* pos_of  = (short*)keys;
  int*   s_idx_sh = (int*)((char*)keys + 15000);
  for (int i = tid; i < HW; i += 1024) pos_of[i] = -1;

  // two-level exclusive prefix scan
  unsigned int inc = sum;
  #pragma unroll
  for (int off = 1; off < 64; off <<= 1) {
    unsigned int t = __shfl_up(inc, off, 64);
    if (lane >= off) inc += t;
  }
  if (lane == 63) partials[w] = inc;
  __syncthreads();
  if (tid < 16) {
    unsigned int v = partials[tid];
    #pragma unroll
    for (int off = 1; off < 16; off <<= 1) {
      unsigned int t = __shfl_up(v, off, 64);
      if (tid >= off) v += t;
    }
    partials[tid] = v;
  }
  __syncthreads();
  unsigned int total = partials[15];
  unsigned int run = (w ? partials[w - 1] : 0u) + inc - sum;
  unsigned int ties = (unsigned int)KSEL - (total & 0xFFFFu);
  #pragma unroll
  for (int e = 0; e < 8; ++e) {
    int i = tid * 8 + e;
    unsigned int p = local[e];
    unsigned int gt_pref = run & 0xFFFFu;
    unsigned int eq_pref = run >> 16;
    bool sel = (p & 1u) || (((p >> 16) != 0u) && eq_pref < ties);
    if (sel) {
      unsigned int pos = gt_pref + (eq_pref < ties ? eq_pref : ties);
      out_idx[b * KSEL + pos] = (float)i;
      s_idx_sh[pos] = i;
      pos_of[i] = (short)pos;
    }
    run += p;
  }
  __syncthreads();

  // ---- counting sort by y' = i % 75 -> off-sorted processing order ----
  // off = (i%75)*100 + i/75; bucket y' groups a 400B plane row. Intra-bucket
  // order (racy atomics) is irrelevant: any permutation is correct (rows are
  // scattered back through perm), locality only needs bucket compactness.
  if (tid < 128) hist[tid] = 0u;
  __syncthreads();
  for (int pos = tid; pos < KSEL; pos += 1024)
    atomicAdd(&hist[s_idx_sh[pos] % H_DIM], 1u);
  __syncthreads();
  if (tid == 0) {
    unsigned int run2 = 0u;
    for (int j = 0; j < H_DIM; ++j) { unsigned int t = hist[j]; hist[j] = run2; run2 += t; }
  }
  __syncthreads();
  for (int pos = tid; pos < KSEL; pos += 1024) {
    int i = s_idx_sh[pos];
    int y = i % H_DIM;
    unsigned int j = atomicAdd(&hist[y], 1u);
    off2_ws[b * KSEL + j] = (i % H_DIM) * W_DIM + i / H_DIM;  // gather quirk
    perm_ws[b * KSEL + j] = pos;
  }

  // neighbor lists; rows padded to 9 (pad=0) so consumers load unconditionally
  for (int i = tid; i < KSEL; i += 1024) {
    int q = s_idx_sh[i];
    int py = q / W_DIM, px = q % W_DIM;
    unsigned short tmp[9];
    int c = 0;
    #pragma unroll
    for (int dy = -1; dy <= 1; ++dy) {
      int y = py + dy;
      if ((unsigned)y >= (unsigned)H_DIM) continue;
      #pragma unroll
      for (int dx = -1; dx <= 1; ++dx) {
        int x = px + dx;
        if ((unsigned)x >= (unsigned)W_DIM) continue;
        short p = pos_of[y * W_DIM + x];
        if (p >= 0) tmp[c++] = (unsigned short)p;
      }
    }
    #pragma unroll
    for (int t = 0; t < 9; ++t)
      nbr[(size_t)(b * KSEL + i) * 9 + t] = (t < c) ? tmp[t] : (unsigned short)0;
    cnt[b * KSEL + i] = (unsigned char)c;
  }
}

// K2 (fused gather+gemm1, DEPTH-3 PIPELINE): G = clip(gather(feat)) @ w1,
// off-sorted rows, perm scatter on the C-write (G bitwise == r3 version).
// r3's loop stalled ~700cy/chunk: the vmcnt drain before ds_write sat in a
// 32-chunk serial chain (r4 more blocks / r5 more waves both null -> it's an
// in-chain latency cost). Here loads for chunk i+3 are issued at iter i and
// consumed (clip+split+ds_write) two full iterations later; LDS is triple-
// buffered so ONE barrier/iter is race-free: the rewrite of buffer i%3
// (chunk i+3, iter i+2) is separated from compute-i's reads by barrier(i+1).
// Full unroll keeps all %3 indices compile-time (no scratch, rule #20).
__global__ __launch_bounds__(256) void gemm1_fused(
    const float* __restrict__ feat, const int* __restrict__ off2_ws,
    const int* __restrict__ perm_ws,
    const unsigned short* __restrict__ w1t_hi,
    const unsigned short* __restrict__ w1t_lo,
    float* __restrict__ G)
{
  __shared__ unsigned short a_hi[3][64][20], a_lo[3][64][20];  // 15.4 KB
  const int b = blockIdx.y;
  const int n0 = blockIdx.x * 64;
  const int tid = threadIdx.x;
  const int lane = tid & 63, w = tid >> 6;
  const int wr = w & 1, wc = w >> 1;
  const int q = lane >> 5, m = lane & 31;
  v16f acc0, acc1;
  #pragma unroll
  for (int i = 0; i < 16; ++i) { acc0[i] = 0.f; acc1[i] = 0.f; }
  const int an = wr * 32 + m;
  const int f0 = wc * 64 + m;
  const int n_st = tid & 63, ks = (tid >> 6) * 4;
  int nidx = n0 + n_st;
  if (nidx > KSEL - 1) nidx = KSEL - 1;   // clamp: dup rows never stored
  const float* fb = feat + (size_t)b * CIN * HW + off2_ws[b * KSEL + nidx];

  float rv[3][4];                          // chunks i+1, i+2, i+3 in flight
  #pragma unroll
  for (int s = 0; s < 3; ++s)
    #pragma unroll
    for (int j = 0; j < 4; ++j)
      rv[s][j] = fb[(size_t)(s * 16 + ks + j) * HW];   // issue chunks 0,1,2
  #pragma unroll
  for (int j = 0; j < 4; ++j) {            // stage chunk 0 -> lds[0]
    float v = fminf(fmaxf(rv[0][j], 0.f), 6.f);
    unsigned short hi = bf16_rne(v);
    a_hi[0][n_st][ks + j] = hi;
    a_lo[0][n_st][ks + j] = bf16_rne(v - bf16_to_f(hi));
  }

  #pragma unroll
  for (int i = 0; i < 32; ++i) {
    if (i + 1 < 32) {                      // stage chunk i+1 (issued iter i-2)
      const int s = (i + 1) % 3;
      #pragma unroll
      for (int j = 0; j < 4; ++j) {
        float v = fminf(fmaxf(rv[s][j], 0.f), 6.f);
        unsigned short hi = bf16_rne(v);
        a_hi[s][n_st][ks + j] = hi;
        a_lo[s][n_st][ks + j] = bf16_rne(v - bf16_to_f(hi));
      }
      if (i + 3 < 32) {                    // reuse freed reg set: issue i+3
        #pragma unroll
        for (int j = 0; j < 4; ++j)
          rv[s][j] = fb[(size_t)((i + 3) * 16 + ks + j) * HW];
      }
    }
    __syncthreads();
    const int p = i % 3;
    const int k0 = i * 16;
    v4s ah0 = *(const v4s*)&a_hi[p][an][q * 8];
    v4s ah1 = *(const v4s*)&a_hi[p][an][q * 8 + 4];
    v4s al0 = *(const v4s*)&a_lo[p][an][q * 8];
    v4s al1 = *(const v4s*)&a_lo[p][an][q * 8 + 4];
    v8s avh = __builtin_shufflevector(ah0, ah1, 0, 1, 2, 3, 4, 5, 6, 7);
    v8s avl = __builtin_shufflevector(al0, al1, 0, 1, 2, 3, 4, 5, 6, 7);
    v8s b0h = *(const v8s*)&w1t_hi[(size_t)f0 * CIN + k0 + q * 8];
    v8s b0l = *(const v8s*)&w1t_lo[(size_t)f0 * CIN + k0 + q * 8];
    v8s b1h = *(const v8s*)&w1t_hi[(size_t)(f0 + 32) * CIN + k0 + q * 8];
    v8s b1l = *(const v8s*)&w1t_lo[(size_t)(f0 + 32) * CIN + k0 + q * 8];
    acc0 = __builtin_amdgcn_mfma_f32_32x32x16_bf16(avh, b0h, acc0, 0, 0, 0);
    acc0 = __builtin_amdgcn_mfma_f32_32x32x16_bf16(avh, b0l, acc0, 0, 0, 0);
    acc0 = __builtin_amdgcn_mfma_f32_32x32x16_bf16(avl, b0h, acc0, 0, 0, 0);
    acc1 = __builtin_amdgcn_mfma_f32_32x32x16_bf16(avh, b1h, acc1, 0, 0, 0);
    acc1 = __builtin_amdgcn_mfma_f32_32x32x16_bf16(avh, b1l, acc1, 0, 0, 0);
    acc1 = __builtin_amdgcn_mfma_f32_32x32x16_bf16(avl, b1h, acc1, 0, 0, 0);
  }
  float* ob = G + (size_t)b * KSEL * FDIM;
  const int* pb = perm_ws + b * KSEL;
  #pragma unroll
  for (int reg = 0; reg < 16; ++reg) {
    int row = n0 + wr * 32 + (reg & 3) + 8 * (reg >> 2) + 4 * q;
    if (row < KSEL) {
      int pr = pb[row];                    // scatter to sorted-pos G row
      ob[(size_t)pr * FDIM + f0]      = acc0[reg];
      ob[(size_t)pr * FDIM + f0 + 32] = acc1[reg];
    }
  }
}

// K3 (fused x1+gemm2): phase 1 computes x1 rows n0..n0+63 (9-neighbor G
// gather + b1), writes fp32 x1 for the out kernel, and drops the bf16 hi/lo
// split straight into XOR-swizzled LDS (col ^ ((row&15)<<3) -> 2-way bank
// aliasing = free). Phase 2 is the split-precision MFMA x1 @ w2 reading A
// from LDS.
__global__ __launch_bounds__(256) void gemm2_fused(
    const float* __restrict__ G, const float* __restrict__ b1,
    const unsigned short* __restrict__ nbr, const unsigned char* __restrict__ cnt,
    const unsigned short* __restrict__ w2t_hi,
    const unsigned short* __restrict__ w2t_lo,
    float* __restrict__ x1, float* __restrict__ Hm)
{
  __shared__ __align__(16) unsigned short xh[64][FDIM];  // 16 KB
  __shared__ __align__(16) unsigned short xl[64][FDIM];  // 16 KB
  const int b = blockIdx.y;
  const int n0 = blockIdx.x * 64;
  const int tid = threadIdx.x;
  const int g = tid >> 5, lane32 = tid & 31;
  const float4* G4 = (const float4*)G + (size_t)b * KSEL * 32;

  #pragma unroll 2
  for (int rr = 0; rr < 8; ++rr) {
    const int r = rr * 8 + g;
    const int node = n0 + r;
    const int nodec = (node > KSEL - 1) ? KSEL - 1 : node;
    const size_t bi = (size_t)b * KSEL + nodec;
    const unsigned short* nb = nbr + bi * 9;
    unsigned short idx[9];
    #pragma unroll
    for (int t = 0; t < 9; ++t) idx[t] = nb[t];
    const int c = cnt[bi];
    float4 v[9];
    #pragma unroll
    for (int t = 0; t < 9; ++t) v[t] = G4[(size_t)idx[t] * 32 + lane32];
    float4 acc = ((const float4*)b1)[nodec * 32 + lane32];
    #pragma unroll
    for (int t = 0; t < 9; ++t) {
      float mk = (t < c) ? 1.f : 0.f;
      acc.x = fmaf(v[t].x, mk, acc.x);
      acc.y = fmaf(v[t].y, mk, acc.y);
      acc.z = fmaf(v[t].z, mk, acc.z);
      acc.w = fmaf(v[t].w, mk, acc.w);
    }
    if (node < KSEL) ((float4*)x1)[bi * 32 + lane32] = acc;
    ushort4 h, l;
    h.x = bf16_rne(acc.x); l.x = bf16_rne(acc.x - bf16_to_f(h.x));
    h.y = bf16_rne(acc.y); l.y = bf16_rne(acc.y - bf16_to_f(h.y));
    h.z = bf16_rne(acc.z); l.z = bf16_rne(acc.z - bf16_to_f(h.z));
    h.w = bf16_rne(acc.w); l.w = bf16_rne(acc.w - bf16_to_f(h.w));
    const int cs = (lane32 * 4) ^ ((r & 15) << 3);   // swizzled col (shorts)
    *(ushort4*)&xh[r][cs] = h;
    *(ushort4*)&xl[r][cs] = l;
  }
  __syncthreads();

  const int lane = tid & 63, w = tid >> 6;
  const int wr = w & 1, wc = w >> 1;
  const int q = lane >> 5, m = lane & 31;
  const int ar = wr * 32 + m;            // local A row in LDS
  const int f0 = wc * 64 + m;
  v16f acc0, acc1;
  #pragma unroll
  for (int i = 0; i < 16; ++i) { acc0[i] = 0.f; acc1[i] = 0.f; }
  #pragma unroll
  for (int k0 = 0; k0 < FDIM; k0 += 16) {
    const int ac = (k0 + q * 8) ^ ((ar & 15) << 3);
    v8s avh = *(const v8s*)&xh[ar][ac];
    v8s avl = *(const v8s*)&xl[ar][ac];
    v8s b0h = *(const v8s*)&w2t_hi[(size_t)f0 * FDIM + k0 + q * 8];
    v8s b0l = *(const v8s*)&w2t_lo[(size_t)f0 * FDIM + k0 + q * 8];
    v8s b1h = *(const v8s*)&w2t_hi[(size_t)(f0 + 32) * FDIM + k0 + q * 8];
    v8s b1l = *(const v8s*)&w2t_lo[(size_t)(f0 + 32) * FDIM + k0 + q * 8];
    acc0 = __builtin_amdgcn_mfma_f32_32x32x16_bf16(avh, b0h, acc0, 0, 0, 0);
    acc0 = __builtin_amdgcn_mfma_f32_32x32x16_bf16(avh, b0l, acc0, 0, 0, 0);
    acc0 = __builtin_amdgcn_mfma_f32_32x32x16_bf16(avl, b0h, acc0, 0, 0, 0);
    acc1 = __builtin_amdgcn_mfma_f32_32x32x16_bf16(avh, b1h, acc1, 0, 0, 0);
    acc1 = __builtin_amdgcn_mfma_f32_32x32x16_bf16(avh, b1l, acc1, 0, 0, 0);
    acc1 = __builtin_amdgcn_mfma_f32_32x32x16_bf16(avl, b1h, acc1, 0, 0, 0);
  }
  float* ob = Hm + (size_t)b * KSEL * FDIM;
  #pragma unroll
  for (int reg = 0; reg < 16; ++reg) {
    int row = n0 + wr * 32 + (reg & 3) + 8 * (reg >> 2) + 4 * q;
    if (row < KSEL) {
      ob[(size_t)row * FDIM + f0]      = acc0[reg];
      ob[(size_t)row * FDIM + f0 + 32] = acc1[reg];
    }
  }
}

// K4: out[i] = tanh(b2[i] + x1[i] + sum_{j in nbr(i)} H[j])
__global__ __launch_bounds__(256) void out_kernel(
    const float* __restrict__ Hm, const float* __restrict__ x1,
    const float* __restrict__ b2,
    const unsigned short* __restrict__ nbr, const unsigned char* __restrict__ cnt,
    float* __restrict__ out)
{
  const int g = threadIdx.x >> 5, lane = threadIdx.x & 31;
  const int node = blockIdx.x * 8 + g;
  const int bb = blockIdx.y;
  const size_t bi = (size_t)bb * KSEL + node;
  const unsigned short* nb = nbr + bi * 9;
  unsigned short idx[9];
  #pragma unroll
  for (int t = 0; t < 9; ++t) idx[t] = nb[t];
  const int c = cnt[bi];
  const float4* H4 = (const float4*)Hm + (size_t)bb * KSEL * 32;
  float4 v[9];
  #pragma unroll
  for (int t = 0; t < 9; ++t) v[t] = H4[(size_t)idx[t] * 32 + lane];
  float4 acc = ((const float4*)b2)[node * 32 + lane];
  float4 xv = ((const float4*)x1)[bi * 32 + lane];
  acc.x += xv.x; acc.y += xv.y; acc.z += xv.z; acc.w += xv.w;
  #pragma unroll
  for (int t = 0; t < 9; ++t) {
    float mk = (t < c) ? 1.f : 0.f;
    acc.x = fmaf(v[t].x, mk, acc.x);
    acc.y = fmaf(v[t].y, mk, acc.y);
    acc.z = fmaf(v[t].z, mk, acc.z);
    acc.w = fmaf(v[t].w, mk, acc.w);
  }
  float4 r;
  r.x = fast_tanh(acc.x); r.y = fast_tanh(acc.y);
  r.z = fast_tanh(acc.z); r.w = fast_tanh(acc.w);
  ((float4*)out)[bi * 32 + lane] = r;
}

extern "C" void kernel_launch(void* const* d_in, const int* in_sizes, int n_in,
                              void* d_out, int out_size, void* d_ws, size_t ws_size,
                              hipStream_t stream) {
  const float* feat = (const float*)d_in[0];
  const float* pred = (const float*)d_in[1];
  const float* w1   = (const float*)d_in[2];
  const float* b1   = (const float*)d_in[3];
  const float* w2   = (const float*)d_in[4];
  const float* b2   = (const float*)d_in[5];
  float* out0 = (float*)d_out;                              // (8,2000,128) fp32
  float* out_idx = out0 + (size_t)BATCH * KSEL * FDIM;      // (8,2000) as fp32

  // workspace layout (256B-aligned), ~25.3 MB
  char* ws = (char*)d_ws;
  int*            off2_ws = (int*)(ws + 0);                  //     64,000 B
  int*            perm_ws = (int*)(ws + 64256);              //     64,000 B
  unsigned short* nbr     = (unsigned short*)(ws + 128512);  //    288,000 B
  unsigned char*  cnt     = (unsigned char*)(ws + 416512);   //     16,000 B
  float*          G       = (float*)(ws + 432640);           //  8,192,000 B
  float*          x1      = (float*)(ws + 8624640);          //  8,192,000 B
  float*          Hm      = (float*)(ws + 16816640);         //  8,192,000 B
  unsigned short* w1t_hi  = (unsigned short*)(ws + 25008640); //   131,072 B
  unsigned short* w1t_lo  = (unsigned short*)(ws + 25139712); //   131,072 B
  unsigned short* w2t_hi  = (unsigned short*)(ws + 25270784); //    32,768 B
  unsigned short* w2t_lo  = (unsigned short*)(ws + 25303552); //    32,768 B

  topk_nbr_kernel<<<BATCH + 8, 1024, 0, stream>>>(
      pred, w1, w2, off2_ws, perm_ws, out_idx, nbr, cnt,
      w1t_hi, w1t_lo, w2t_hi, w2t_lo);
  gemm1_fused<<<dim3(32, BATCH), 256, 0, stream>>>(
      feat, off2_ws, perm_ws, w1t_hi, w1t_lo, G);
  gemm2_fused<<<dim3(32, BATCH), 256, 0, stream>>>(G, b1, nbr, cnt, w2t_hi, w2t_lo, x1, Hm);
  out_kernel<<<dim3(KSEL / 8, BATCH), 256, 0, stream>>>(Hm, x1, b2, nbr, cnt, out0);
}